// Round 1
// baseline (342.504 us; speedup 1.0000x reference)
//
#include <hip/hip_runtime.h>

// ---------------------------------------------------------------------------
// MultiQueryAttention: B=4 S=2048 E=1024 H=16 D=64 Q=4
// ref: q=x@Wq^T+bq (per qi), k=x@Wk^T+bk, v=x@Wv^T+bv
//      scores[qi,b,s,h,g] = dot_d(q[h],k[g])/8 ; softmax over g (16 heads!)
//      out[qi,b,s,h,d] = sum_g p*v[g,d]
//      t[b, 128h + s/16, 64(s%16)+d] = sum_qi out   (torch transpose+reshape)
//      final = t @ Wo^T + bo   (fp32 out)
// ---------------------------------------------------------------------------

typedef __bf16 bf16x8 __attribute__((ext_vector_type(8)));
typedef float f32x4 __attribute__((ext_vector_type(4)));

__device__ __forceinline__ unsigned short f2b(float f) {
  unsigned u = __float_as_uint(f);
  return (unsigned short)((u + 0x7fffu + ((u >> 16) & 1u)) >> 16);  // RNE
}
__device__ __forceinline__ float bl(unsigned u) { return __uint_as_float(u << 16); }
__device__ __forceinline__ float bh(unsigned u) { return __uint_as_float(u & 0xffff0000u); }

__device__ __forceinline__ void async16(const void* g, void* l) {
  __builtin_amdgcn_global_load_lds(
      (const __attribute__((address_space(1))) void*)g,
      (__attribute__((address_space(3))) void*)l, 16, 0, 0);
}

// --------------------------- fp32 -> bf16 convert ---------------------------
__global__ void cvt_f32_bf16(const float* __restrict__ s, unsigned short* __restrict__ d, int n4) {
  int i = blockIdx.x * 256 + threadIdx.x;
  if (i >= n4) return;
  float4 v = ((const float4*)s)[i];
  uint2 o;
  o.x = (unsigned)f2b(v.x) | ((unsigned)f2b(v.y) << 16);
  o.y = (unsigned)f2b(v.z) | ((unsigned)f2b(v.w) << 16);
  ((uint2*)d)[i] = o;
}

__global__ void bias_concat(const float* __restrict__ bq, const float* __restrict__ bk,
                            const float* __restrict__ bv, float* __restrict__ dst) {
  int i = blockIdx.x * 256 + threadIdx.x;  // 0..6143
  float v = (i < 4096) ? bq[i] : (i < 5120 ? bk[i - 4096] : bv[i - 5120]);
  dst[i] = v;
}

// --------------------------- C = A * Bt^T + bias ----------------------------
// A: MxK bf16 row-major, Bt: NxK bf16 row-major ("out,in" torch layout)
// 128x128 block tile, BK=64, 256 threads = 4 waves in 2x2, each 64x64 (4x4 MFMAs)
// m97 structure: global_load_lds width=16, 2-barrier K-loop.
template <typename OutT>
__global__ __launch_bounds__(256) void gemm_bt(const unsigned short* __restrict__ A,
                                               const unsigned short* __restrict__ Bt,
                                               const float* __restrict__ bias,
                                               OutT* __restrict__ C, int M, int N, int K) {
  __shared__ __align__(16) unsigned short As[128 * 64];
  __shared__ __align__(16) unsigned short Bs[128 * 64];
  const int t = threadIdx.x;
  const int lane = t & 63, w = t >> 6;
  const int wm = (w >> 1) * 64, wn = (w & 1) * 64;
  const int lr = lane & 15, lq = lane >> 4;
  const int bm0 = blockIdx.y * 128, bn0 = blockIdx.x * 128;

  f32x4 zero = {0.f, 0.f, 0.f, 0.f};
  f32x4 acc[4][4];
#pragma unroll
  for (int i = 0; i < 4; ++i)
#pragma unroll
    for (int j = 0; j < 4; ++j) acc[i][j] = zero;

  for (int k0 = 0; k0 < K; k0 += 64) {
    __syncthreads();  // protect LDS from previous iter's readers
#pragma unroll
    for (int j = 0; j < 4; ++j) {
      int slot = j * 256 + t;              // 1024 slots x 16B = 16KB tile
      int r = slot >> 3, c = (slot & 7) * 8;
      async16(A + (size_t)(bm0 + r) * K + k0 + c, As + slot * 8);
      async16(Bt + (size_t)(bn0 + r) * K + k0 + c, Bs + slot * 8);
    }
    __syncthreads();  // drains vmcnt before barrier -> LDS tiles ready
#pragma unroll
    for (int kk = 0; kk < 64; kk += 32) {
      bf16x8 af[4], bfr[4];
#pragma unroll
      for (int i = 0; i < 4; ++i)
        af[i] = *(const bf16x8*)(As + (wm + i * 16 + lr) * 64 + kk + lq * 8);
#pragma unroll
      for (int j = 0; j < 4; ++j)
        bfr[j] = *(const bf16x8*)(Bs + (wn + j * 16 + lr) * 64 + kk + lq * 8);
#pragma unroll
      for (int i = 0; i < 4; ++i)
#pragma unroll
        for (int j = 0; j < 4; ++j)
          acc[i][j] = __builtin_amdgcn_mfma_f32_16x16x32_bf16(af[i], bfr[j], acc[i][j], 0, 0, 0);
    }
  }

  // C/D layout: col = lane&15, row = (lane>>4)*4 + reg  [measured m89/m91]
#pragma unroll
  for (int i = 0; i < 4; ++i) {
    int gr = bm0 + wm + i * 16 + lq * 4;
#pragma unroll
    for (int j = 0; j < 4; ++j) {
      int gc = bn0 + wn + j * 16 + lr;
      float bsv = bias[gc];
#pragma unroll
      for (int r = 0; r < 4; ++r) {
        float vv = acc[i][j][r] + bsv;
        if constexpr (sizeof(OutT) == 2)
          C[(size_t)(gr + r) * N + gc] = (OutT)f2b(vv);
        else
          C[(size_t)(gr + r) * N + gc] = vv;
      }
    }
  }
}

// ------------------- per-position head-softmax attention --------------------
// qkv: (8192, 6144) bf16 rows = b*2048+s; cols [0,4096)=q(qi,h,d) [4096,5120)=k [5120,6144)=v
// One wave per position. Writes t[b, 128h + s/16, 64(s%16)+d] = sum_qi out.
__global__ __launch_bounds__(256) void attn_scatter(const unsigned short* __restrict__ qkv,
                                                    unsigned short* __restrict__ t) {
  __shared__ __align__(16) unsigned short vs[4][1024];
  __shared__ float ps[4][16 * 17];
  const int w = threadIdx.x >> 6, lane = threadIdx.x & 63;
  const int pos = blockIdx.x * 4 + w;  // 0..8191
  const int b = pos >> 11, s = pos & 2047;
  const unsigned short* row = qkv + (size_t)pos * 6144;
  unsigned short* vw = vs[w];
  float* pw = ps[w];
  const int lr = lane & 15, lq = lane >> 4;

  // stage V (16x64 bf16) into LDS, raw (g,d) layout
  {
    const uint4* sv = (const uint4*)(row + 5120);
    uint4* dv = (uint4*)vw;
    dv[lane * 2] = sv[lane * 2];
    dv[lane * 2 + 1] = sv[lane * 2 + 1];
  }
  // K fragments (B-operand, n=g=lane&15, k=d) — invariant over qi
  bf16x8 kf0 = *(const bf16x8*)(row + 4096 + lr * 64 + lq * 8);
  bf16x8 kf1 = *(const bf16x8*)(row + 4096 + lr * 64 + 32 + lq * 8);

  float oa[16];
#pragma unroll
  for (int i = 0; i < 16; ++i) oa[i] = 0.f;
  const int h2 = lr, dseg = lq;  // PV/output lane assignment

#pragma unroll
  for (int qi = 0; qi < 4; ++qi) {
    bf16x8 qf0 = *(const bf16x8*)(row + qi * 1024 + lr * 64 + lq * 8);
    bf16x8 qf1 = *(const bf16x8*)(row + qi * 1024 + lr * 64 + 32 + lq * 8);
    f32x4 sc = {0.f, 0.f, 0.f, 0.f};
    sc = __builtin_amdgcn_mfma_f32_16x16x32_bf16(qf0, kf0, sc, 0, 0, 0);
    sc = __builtin_amdgcn_mfma_f32_16x16x32_bf16(qf1, kf1, sc, 0, 0, 0);
    // sc[r] = scores[h=lq*4+r][g=lr]; softmax over g = across 16 lanes of quad
#pragma unroll
    for (int r = 0; r < 4; ++r) {
      float x = sc[r] * 0.125f;
      float m = x;
#pragma unroll
      for (int d = 1; d < 16; d <<= 1) m = fmaxf(m, __shfl_xor(m, d));
      float e = __expf(x - m);
      float sum = e;
#pragma unroll
      for (int d = 1; d < 16; d <<= 1) sum += __shfl_xor(sum, d);
      pw[(lq * 4 + r) * 17 + lr] = e / sum;  // P[h][g], +17 stride kills conflicts
    }
    __syncthreads();  // uniform across all 4 waves
    // out[h, dseg*16 + 0..15] += sum_g P[h][g] * v[g, d]
#pragma unroll
    for (int g = 0; g < 16; ++g) {
      float p = pw[h2 * 17 + g];
      const uint4* vp = (const uint4*)(vw + g * 64 + dseg * 16);
      uint4 a = vp[0], c = vp[1];
      oa[0] += p * bl(a.x);  oa[1] += p * bh(a.x);
      oa[2] += p * bl(a.y);  oa[3] += p * bh(a.y);
      oa[4] += p * bl(a.z);  oa[5] += p * bh(a.z);
      oa[6] += p * bl(a.w);  oa[7] += p * bh(a.w);
      oa[8] += p * bl(c.x);  oa[9] += p * bh(c.x);
      oa[10] += p * bl(c.y); oa[11] += p * bh(c.y);
      oa[12] += p * bl(c.z); oa[13] += p * bh(c.z);
      oa[14] += p * bl(c.w); oa[15] += p * bh(c.w);
    }
    __syncthreads();  // before next qi overwrites pw
  }

  // scatter: t[b, 128*h + s/16, 64*(s%16) + dseg*16 + i]
  size_t off = ((size_t)(b * 2048 + 128 * h2 + (s >> 4))) * 1024 + 64 * (s & 15) + dseg * 16;
  uint4 p0, p1;
  p0.x = (unsigned)f2b(oa[0]) | ((unsigned)f2b(oa[1]) << 16);
  p0.y = (unsigned)f2b(oa[2]) | ((unsigned)f2b(oa[3]) << 16);
  p0.z = (unsigned)f2b(oa[4]) | ((unsigned)f2b(oa[5]) << 16);
  p0.w = (unsigned)f2b(oa[6]) | ((unsigned)f2b(oa[7]) << 16);
  p1.x = (unsigned)f2b(oa[8]) | ((unsigned)f2b(oa[9]) << 16);
  p1.y = (unsigned)f2b(oa[10]) | ((unsigned)f2b(oa[11]) << 16);
  p1.z = (unsigned)f2b(oa[12]) | ((unsigned)f2b(oa[13]) << 16);
  p1.w = (unsigned)f2b(oa[14]) | ((unsigned)f2b(oa[15]) << 16);
  ((uint4*)(t + off))[0] = p0;
  ((uint4*)(t + off + 8))[0] = p1;
}

// ---------------------------------------------------------------------------
extern "C" void kernel_launch(void* const* d_in, const int* in_sizes, int n_in,
                              void* d_out, int out_size, void* d_ws, size_t ws_size,
                              hipStream_t stream) {
  const float* x  = (const float*)d_in[0];
  const float* Wq = (const float*)d_in[1];
  const float* bq = (const float*)d_in[2];
  const float* Wk = (const float*)d_in[3];
  const float* bk = (const float*)d_in[4];
  const float* Wv = (const float*)d_in[5];
  const float* bv = (const float*)d_in[6];
  const float* Wo = (const float*)d_in[7];
  const float* bo = (const float*)d_in[8];
  float* out = (float*)d_out;

  char* ws = (char*)d_ws;
  unsigned short* xb      = (unsigned short*)(ws + 0);         // 8192x1024 bf16 (16MB); aliased as t later
  unsigned short* wcat    = (unsigned short*)(ws + 16777216);  // 6144x1024 bf16 (12MB): Wq|Wk|Wv
  unsigned short* wo_b    = (unsigned short*)(ws + 29360128);  // 1024x1024 bf16 (2MB)
  float*          biascat = (float*)(ws + 31457280);           // 6144 fp32
  unsigned short* qkv     = (unsigned short*)(ws + 31481856);  // 8192x6144 bf16 (96MB)
  unsigned short* t       = xb;  // safe alias: xb dead after QKV GEMM

  cvt_f32_bf16<<<8192, 256, 0, stream>>>(x, xb, 8388608 / 4);
  cvt_f32_bf16<<<4096, 256, 0, stream>>>(Wq, wcat, 4194304 / 4);
  cvt_f32_bf16<<<1024, 256, 0, stream>>>(Wk, wcat + 4194304, 1048576 / 4);
  cvt_f32_bf16<<<1024, 256, 0, stream>>>(Wv, wcat + 5242880, 1048576 / 4);
  cvt_f32_bf16<<<1024, 256, 0, stream>>>(Wo, wo_b, 1048576 / 4);
  bias_concat<<<24, 256, 0, stream>>>(bq, bk, bv, biascat);

  // QKV: (8192x1024) x (6144x1024)^T -> 8192x6144 bf16
  gemm_bt<unsigned short><<<dim3(48, 64), 256, 0, stream>>>(xb, wcat, biascat, qkv, 8192, 6144, 1024);
  // attention + permute/sum scatter -> t (8192x1024 bf16)
  attn_scatter<<<2048, 256, 0, stream>>>(qkv, t);
  // final: t x Wo^T + bo -> fp32 out
  gemm_bt<float><<<dim3(8, 64), 256, 0, stream>>>(t, wo_b, bo, out, 8192, 1024, 1024);
}

// Round 2
// 314.149 us; speedup vs baseline: 1.0903x; 1.0903x over previous
//
#include <hip/hip_runtime.h>

// ---------------------------------------------------------------------------
// MultiQueryAttention: B=4 S=2048 E=1024 H=16 D=64 Q=4
// ref: q=x@Wq^T+bq (per qi), k=x@Wk^T+bk, v=x@Wv^T+bv
//      scores[qi,b,s,h,g] = dot_d(q[h],k[g])/8 ; softmax over g (16 heads!)
//      out[qi,b,s,h,d] = sum_g p*v[g,d]
//      t[b, 128h + s/16, 64(s%16)+d] = sum_qi out   (torch transpose+reshape)
//      final = t @ Wo^T + bo   (fp32 out)
// ---------------------------------------------------------------------------

typedef __bf16 bf16x8 __attribute__((ext_vector_type(8)));
typedef float f32x4 __attribute__((ext_vector_type(4)));

__device__ __forceinline__ unsigned short f2b(float f) {
  unsigned u = __float_as_uint(f);
  return (unsigned short)((u + 0x7fffu + ((u >> 16) & 1u)) >> 16);  // RNE
}
__device__ __forceinline__ float bl(unsigned u) { return __uint_as_float(u << 16); }
__device__ __forceinline__ float bh(unsigned u) { return __uint_as_float(u & 0xffff0000u); }

__device__ __forceinline__ void async16(const void* g, void* l) {
  __builtin_amdgcn_global_load_lds(
      (const __attribute__((address_space(1))) void*)g,
      (__attribute__((address_space(3))) void*)l, 16, 0, 0);
}

// --------------------------- fp32 -> bf16 convert ---------------------------
__global__ void cvt_f32_bf16(const float* __restrict__ s, unsigned short* __restrict__ d, int n4) {
  int i = blockIdx.x * 256 + threadIdx.x;
  if (i >= n4) return;
  float4 v = ((const float4*)s)[i];
  uint2 o;
  o.x = (unsigned)f2b(v.x) | ((unsigned)f2b(v.y) << 16);
  o.y = (unsigned)f2b(v.z) | ((unsigned)f2b(v.w) << 16);
  ((uint2*)d)[i] = o;
}

__global__ void bias_concat(const float* __restrict__ bq, const float* __restrict__ bk,
                            const float* __restrict__ bv, float* __restrict__ dst) {
  int i = blockIdx.x * 256 + threadIdx.x;  // 0..6143
  float v = (i < 4096) ? bq[i] : (i < 5120 ? bk[i - 4096] : bv[i - 5120]);
  dst[i] = v;
}

// --------------------------- C = A * Bt^T + bias ----------------------------
// A: MxK bf16 row-major, Bt: NxK bf16 row-major ("out,in" torch layout)
// 128x128 block tile, BK=64, 256 threads = 4 waves in 2x2, each 64x64 (4x4 MFMAs)
// m97 structure + XOR granule swizzle: LDS phys granule p of row r holds
// logical granule p^(r&7) (swizzle applied on the SOURCE address, since
// global_load_lds forces dest = base + lane*16). Fragment reads then spread
// 8 lanes on each of the 8 granule groups -> 8-pass (optimal) b128 reads.
template <typename OutT>
__global__ __launch_bounds__(256) void gemm_bt(const unsigned short* __restrict__ A,
                                               const unsigned short* __restrict__ Bt,
                                               const float* __restrict__ bias,
                                               OutT* __restrict__ C, int M, int N, int K) {
  __shared__ __align__(16) unsigned short As[128 * 64];
  __shared__ __align__(16) unsigned short Bs[128 * 64];
  const int t = threadIdx.x;
  const int lane = t & 63, w = t >> 6;
  const int wm = (w >> 1) * 64, wn = (w & 1) * 64;
  const int lr = lane & 15, lq = lane >> 4;
  const int bm0 = blockIdx.y * 128, bn0 = blockIdx.x * 128;

  f32x4 zero = {0.f, 0.f, 0.f, 0.f};
  f32x4 acc[4][4];
#pragma unroll
  for (int i = 0; i < 4; ++i)
#pragma unroll
    for (int j = 0; j < 4; ++j) acc[i][j] = zero;

  // physical granules for fragment reads (XOR swizzle by row&7 == lr&7)
  const int swz = lr & 7;

  for (int k0 = 0; k0 < K; k0 += 64) {
    __syncthreads();  // protect LDS from previous iter's readers
#pragma unroll
    for (int j = 0; j < 4; ++j) {
      int slot = j * 256 + t;              // 1024 slots x 16B = 16KB tile
      int r = slot >> 3;                   // row 0..127
      int gran = slot & 7;                 // physical granule
      int c = (gran ^ (r & 7)) * 8;        // logical granule it must hold
      async16(A + (size_t)(bm0 + r) * K + k0 + c, As + slot * 8);
      async16(Bt + (size_t)(bn0 + r) * K + k0 + c, Bs + slot * 8);
    }
    __syncthreads();  // drains vmcnt before barrier -> LDS tiles ready
#pragma unroll
    for (int kk = 0; kk < 64; kk += 32) {
      const int kg = kk >> 3;  // 0 or 4
      bf16x8 af[4], bfr[4];
#pragma unroll
      for (int i = 0; i < 4; ++i)
        af[i] = *(const bf16x8*)(As + (wm + i * 16 + lr) * 64 + (((kg + lq) ^ swz) << 3));
#pragma unroll
      for (int j = 0; j < 4; ++j)
        bfr[j] = *(const bf16x8*)(Bs + (wn + j * 16 + lr) * 64 + (((kg + lq) ^ swz) << 3));
#pragma unroll
      for (int i = 0; i < 4; ++i)
#pragma unroll
        for (int j = 0; j < 4; ++j)
          acc[i][j] = __builtin_amdgcn_mfma_f32_16x16x32_bf16(af[i], bfr[j], acc[i][j], 0, 0, 0);
    }
  }

  // C/D layout: col = lane&15, row = (lane>>4)*4 + reg  [measured m89/m91]
#pragma unroll
  for (int i = 0; i < 4; ++i) {
    int gr = bm0 + wm + i * 16 + lq * 4;
#pragma unroll
    for (int j = 0; j < 4; ++j) {
      int gc = bn0 + wn + j * 16 + lr;
      float bsv = bias[gc];
#pragma unroll
      for (int r = 0; r < 4; ++r) {
        float vv = acc[i][j][r] + bsv;
        if constexpr (sizeof(OutT) == 2)
          C[(size_t)(gr + r) * N + gc] = (OutT)f2b(vv);
        else
          C[(size_t)(gr + r) * N + gc] = vv;
      }
    }
  }
}

// ------------------- per-position head-softmax attention --------------------
// qkv: (8192, 6144) bf16 rows = b*2048+s; cols [0,4096)=q(qi,h,d) [4096,5120)=k [5120,6144)=v
// One wave per position. Writes t[b, 128h + s/16, 64(s%16)+d] = sum_qi out.
__global__ __launch_bounds__(256) void attn_scatter(const unsigned short* __restrict__ qkv,
                                                    unsigned short* __restrict__ t) {
  __shared__ __align__(16) unsigned short vs[4][1024];
  __shared__ float ps[4][16 * 17];
  const int w = threadIdx.x >> 6, lane = threadIdx.x & 63;
  const int pos = blockIdx.x * 4 + w;  // 0..8191
  const int b = pos >> 11, s = pos & 2047;
  const unsigned short* row = qkv + (size_t)pos * 6144;
  unsigned short* vw = vs[w];
  float* pw = ps[w];
  const int lr = lane & 15, lq = lane >> 4;

  // stage V (16x64 bf16) into LDS, raw (g,d) layout
  {
    const uint4* sv = (const uint4*)(row + 5120);
    uint4* dv = (uint4*)vw;
    dv[lane * 2] = sv[lane * 2];
    dv[lane * 2 + 1] = sv[lane * 2 + 1];
  }
  // K fragments (B-operand, n=g=lane&15, k=d) — invariant over qi
  bf16x8 kf0 = *(const bf16x8*)(row + 4096 + lr * 64 + lq * 8);
  bf16x8 kf1 = *(const bf16x8*)(row + 4096 + lr * 64 + 32 + lq * 8);

  float oa[16];
#pragma unroll
  for (int i = 0; i < 16; ++i) oa[i] = 0.f;
  const int h2 = lr, dseg = lq;  // PV/output lane assignment

#pragma unroll
  for (int qi = 0; qi < 4; ++qi) {
    bf16x8 qf0 = *(const bf16x8*)(row + qi * 1024 + lr * 64 + lq * 8);
    bf16x8 qf1 = *(const bf16x8*)(row + qi * 1024 + lr * 64 + 32 + lq * 8);
    f32x4 sc = {0.f, 0.f, 0.f, 0.f};
    sc = __builtin_amdgcn_mfma_f32_16x16x32_bf16(qf0, kf0, sc, 0, 0, 0);
    sc = __builtin_amdgcn_mfma_f32_16x16x32_bf16(qf1, kf1, sc, 0, 0, 0);
    // sc[r] = scores[h=lq*4+r][g=lr]; softmax over g = across 16 lanes of quad
#pragma unroll
    for (int r = 0; r < 4; ++r) {
      float x = sc[r] * 0.125f;
      float m = x;
#pragma unroll
      for (int d = 1; d < 16; d <<= 1) m = fmaxf(m, __shfl_xor(m, d));
      float e = __expf(x - m);
      float sum = e;
#pragma unroll
      for (int d = 1; d < 16; d <<= 1) sum += __shfl_xor(sum, d);
      pw[(lq * 4 + r) * 17 + lr] = e / sum;  // P[h][g], +17 stride kills conflicts
    }
    __syncthreads();  // uniform across all 4 waves
    // out[h, dseg*16 + 0..15] += sum_g P[h][g] * v[g, d]
#pragma unroll
    for (int g = 0; g < 16; ++g) {
      float p = pw[h2 * 17 + g];
      const uint4* vp = (const uint4*)(vw + g * 64 + dseg * 16);
      uint4 a = vp[0], c = vp[1];
      oa[0] += p * bl(a.x);  oa[1] += p * bh(a.x);
      oa[2] += p * bl(a.y);  oa[3] += p * bh(a.y);
      oa[4] += p * bl(a.z);  oa[5] += p * bh(a.z);
      oa[6] += p * bl(a.w);  oa[7] += p * bh(a.w);
      oa[8] += p * bl(c.x);  oa[9] += p * bh(c.x);
      oa[10] += p * bl(c.y); oa[11] += p * bh(c.y);
      oa[12] += p * bl(c.z); oa[13] += p * bh(c.z);
      oa[14] += p * bl(c.w); oa[15] += p * bh(c.w);
    }
    __syncthreads();  // before next qi overwrites pw
  }

  // scatter: t[b, 128*h + s/16, 64*(s%16) + dseg*16 + i]
  size_t off = ((size_t)(b * 2048 + 128 * h2 + (s >> 4))) * 1024 + 64 * (s & 15) + dseg * 16;
  uint4 p0, p1;
  p0.x = (unsigned)f2b(oa[0]) | ((unsigned)f2b(oa[1]) << 16);
  p0.y = (unsigned)f2b(oa[2]) | ((unsigned)f2b(oa[3]) << 16);
  p0.z = (unsigned)f2b(oa[4]) | ((unsigned)f2b(oa[5]) << 16);
  p0.w = (unsigned)f2b(oa[6]) | ((unsigned)f2b(oa[7]) << 16);
  p1.x = (unsigned)f2b(oa[8]) | ((unsigned)f2b(oa[9]) << 16);
  p1.y = (unsigned)f2b(oa[10]) | ((unsigned)f2b(oa[11]) << 16);
  p1.z = (unsigned)f2b(oa[12]) | ((unsigned)f2b(oa[13]) << 16);
  p1.w = (unsigned)f2b(oa[14]) | ((unsigned)f2b(oa[15]) << 16);
  ((uint4*)(t + off))[0] = p0;
  ((uint4*)(t + off + 8))[0] = p1;
}

// ---------------------------------------------------------------------------
extern "C" void kernel_launch(void* const* d_in, const int* in_sizes, int n_in,
                              void* d_out, int out_size, void* d_ws, size_t ws_size,
                              hipStream_t stream) {
  const float* x  = (const float*)d_in[0];
  const float* Wq = (const float*)d_in[1];
  const float* bq = (const float*)d_in[2];
  const float* Wk = (const float*)d_in[3];
  const float* bk = (const float*)d_in[4];
  const float* Wv = (const float*)d_in[5];
  const float* bv = (const float*)d_in[6];
  const float* Wo = (const float*)d_in[7];
  const float* bo = (const float*)d_in[8];
  float* out = (float*)d_out;

  char* ws = (char*)d_ws;
  unsigned short* xb      = (unsigned short*)(ws + 0);         // 8192x1024 bf16 (16MB); aliased as t later
  unsigned short* wcat    = (unsigned short*)(ws + 16777216);  // 6144x1024 bf16 (12MB): Wq|Wk|Wv
  unsigned short* wo_b    = (unsigned short*)(ws + 29360128);  // 1024x1024 bf16 (2MB)
  float*          biascat = (float*)(ws + 31457280);           // 6144 fp32
  unsigned short* qkv     = (unsigned short*)(ws + 31481856);  // 8192x6144 bf16 (96MB)
  unsigned short* t       = xb;  // safe alias: xb dead after QKV GEMM

  cvt_f32_bf16<<<8192, 256, 0, stream>>>(x, xb, 8388608 / 4);
  cvt_f32_bf16<<<4096, 256, 0, stream>>>(Wq, wcat, 4194304 / 4);
  cvt_f32_bf16<<<1024, 256, 0, stream>>>(Wk, wcat + 4194304, 1048576 / 4);
  cvt_f32_bf16<<<1024, 256, 0, stream>>>(Wv, wcat + 5242880, 1048576 / 4);
  cvt_f32_bf16<<<1024, 256, 0, stream>>>(Wo, wo_b, 1048576 / 4);
  bias_concat<<<24, 256, 0, stream>>>(bq, bk, bv, biascat);

  // QKV: (8192x1024) x (6144x1024)^T -> 8192x6144 bf16
  gemm_bt<unsigned short><<<dim3(48, 64), 256, 0, stream>>>(xb, wcat, biascat, qkv, 8192, 6144, 1024);
  // attention + permute/sum scatter -> t (8192x1024 bf16)
  attn_scatter<<<2048, 256, 0, stream>>>(qkv, t);
  // final: t x Wo^T + bo -> fp32 out
  gemm_bt<float><<<dim3(8, 64), 256, 0, stream>>>(t, wo_b, bo, out, 8192, 1024, 1024);
}